// Round 1
// baseline (1850.426 us; speedup 1.0000x reference)
//
#include <hip/hip_runtime.h>
#include <hip/hip_bf16.h>

#define BSZ 128
#define NSQ 1024
#define NSTEPC 8
#define IND 768
#define HIDD 512
#define G4D 2048
#define MLPD 512
#define KXD 1280
#define NEGV -100000.0f
#define KSG 16   // K-split chunks for gates gemm (1280/16 = 80 = 5 tiles)
#define KSH 8    // K-split chunks for hproj gemm (512/8 = 64 = 4 tiles)
#define MSPLIT 4 // m-split for scores kernel

__device__ __forceinline__ float bf2f(unsigned short u) {
  unsigned int x = ((unsigned int)u) << 16;
  return __builtin_bit_cast(float, x);
}
__device__ __forceinline__ unsigned short f2bf(float x) {
  __hip_bfloat16 h = __float2bfloat16(x);
  return __builtin_bit_cast(unsigned short, h);
}

__device__ __forceinline__ float4 cp_load(const float* p) { return *(const float4*)p; }
__device__ __forceinline__ float4 cp_load(const __hip_bfloat16* p) {
  const ushort4 u = *(const ushort4*)p;
  return make_float4(bf2f(u.x), bf2f(u.y), bf2f(u.z), bf2f(u.w));
}
__device__ __forceinline__ void cp_store4(float* p, float a, float b, float c, float d) {
  *(float4*)p = make_float4(a, b, c, d);
}
__device__ __forceinline__ void cp_store4(__hip_bfloat16* p, float a, float b, float c, float d) {
  *(ushort4*)p = make_ushort4(f2bf(a), f2bf(b), f2bf(c), f2bf(d));
}

// tanh(x) = 1 - 2/(e^{2x}+1); v_exp_f32 + v_rcp_f32 are ~1 ulp -> ~2e-7 abs err
__device__ __forceinline__ float tanh_fast(float x) {
  x = fminf(fmaxf(x, -15.0f), 15.0f);
  float e = __builtin_amdgcn_exp2f(x * 2.8853900817779268f); // e^{2x}
  float r = __builtin_amdgcn_rcpf(e + 1.0f);
  return fmaf(-2.0f, r, 1.0f);
}

// ---------------- init: mask from ctx_len, xh = [target_emb | 0], c=0, lp=0
__global__ __launch_bounds__(256) void k_init(
    const float* __restrict__ te, const int* __restrict__ cl,
    float* __restrict__ mask, float* __restrict__ xh,
    float* __restrict__ cst, float* __restrict__ lp) {
  const int b = blockIdx.x, tid = threadIdx.x;
  const int L = cl[b];
  for (int n = tid; n < NSQ; n += 256) mask[(size_t)b*NSQ + n] = (n >= L) ? NEGV : 0.0f;
  for (int d = tid; d < IND; d += 256) xh[(size_t)b*KXD + d] = te[(size_t)b*IND + d];
  for (int j = tid; j < HIDD; j += 256) {
    xh[(size_t)b*KXD + IND + j] = 0.0f;
    cst[(size_t)b*HIDD + j] = 0.0f;
  }
  if (tid == 0) lp[b] = 0.0f;
}

// ---------------- ctx_part GEMM: cp[b][m][n] = sum_k ctx[b,n,k]*W1c[m,k] + b1[m]
// BM=128 (rows i=b*NS+n), BN=128 (m), BK=16, 256 thr, 8x8 micro
template<typename CPT>
__global__ __launch_bounds__(256) void k_ctx_gemm(
    const float* __restrict__ A, const float* __restrict__ W,
    const float* __restrict__ bias, CPT* __restrict__ cp) {
  __shared__ float As[16][128];
  __shared__ float Bs[16][132];
  const int i0 = blockIdx.y * 128;
  const int m0 = blockIdx.x * 128;
  const int tid = threadIdx.x;
  const int tn = tid & 15;   // m-group
  const int ta = tid >> 4;   // i-group
  float acc[8][8] = {};      // [mi][ri]
  for (int k0 = 0; k0 < IND; k0 += 16) {
#pragma unroll
    for (int u = 0; u < 2; ++u) {
      const int v = tid + u * 256;
      const int r = v >> 2, kc = v & 3;
      const float4 a4 = *(const float4*)(A + (size_t)(i0 + r) * IND + k0 + kc * 4);
      As[kc*4+0][r] = a4.x; As[kc*4+1][r] = a4.y; As[kc*4+2][r] = a4.z; As[kc*4+3][r] = a4.w;
      const float4 b4 = *(const float4*)(W + (size_t)(m0 + r) * IND + k0 + kc * 4);
      Bs[kc*4+0][r] = b4.x; Bs[kc*4+1][r] = b4.y; Bs[kc*4+2][r] = b4.z; Bs[kc*4+3][r] = b4.w;
    }
    __syncthreads();
#pragma unroll
    for (int kk = 0; kk < 16; ++kk) {
      float av[8], bv[8];
#pragma unroll
      for (int q = 0; q < 8; ++q) av[q] = As[kk][ta*8+q];
#pragma unroll
      for (int q = 0; q < 8; ++q) bv[q] = Bs[kk][tn*8+q];
#pragma unroll
      for (int mi = 0; mi < 8; ++mi)
#pragma unroll
        for (int ri = 0; ri < 8; ++ri)
          acc[mi][ri] = fmaf(bv[mi], av[ri], acc[mi][ri]);
    }
    __syncthreads();
  }
  const int bidx = i0 >> 10;
  const int nbase = (i0 & 1023) + ta * 8;
#pragma unroll
  for (int mi = 0; mi < 8; ++mi) {
    const int m = m0 + tn * 8 + mi;
    const float bb = bias[m];
    CPT* p = cp + ((size_t)bidx * MLPD + m) * NSQ + nbase;
    cp_store4(p + 0, acc[mi][0]+bb, acc[mi][1]+bb, acc[mi][2]+bb, acc[mi][3]+bb);
    cp_store4(p + 4, acc[mi][4]+bb, acc[mi][5]+bb, acc[mi][6]+bb, acc[mi][7]+bb);
  }
}

// ---------------- K-split partial GEMM: P[kc][i][n] = sum_{k in chunk} A[i,acol+k]*B(n,k)
// M=128 fixed, BN=128, BK=16; B(n,k) = k<kb ? B0[n*ldb0+k] : B1[n*ldb1+k-kb]
__global__ __launch_bounds__(256) void k_pgemm(
    const float* __restrict__ A, int lda, int acol,
    const float* __restrict__ B0, int ldb0, int kb,
    const float* __restrict__ B1, int ldb1,
    int kTiles, int N, float* __restrict__ P) {
  __shared__ float As[16][128];
  __shared__ float Bs[16][132];
  const int n0 = blockIdx.x * 128;
  const int kc0 = blockIdx.y * kTiles * 16;
  const int tid = threadIdx.x;
  const int tn = tid & 15;   // n-group
  const int ta = tid >> 4;   // i-group
  float acc[8][8] = {};      // [ri][ni]
  for (int t = 0; t < kTiles; ++t) {
    const int k0 = kc0 + t * 16;
#pragma unroll
    for (int u = 0; u < 2; ++u) {
      const int v = tid + u * 256;
      const int r = v >> 2, kc = v & 3;
      const float4 a4 = *(const float4*)(A + (size_t)r * lda + acol + k0 + kc * 4);
      As[kc*4+0][r] = a4.x; As[kc*4+1][r] = a4.y; As[kc*4+2][r] = a4.z; As[kc*4+3][r] = a4.w;
      const float* bp = (k0 < kb) ? (B0 + (size_t)(n0 + r) * ldb0 + k0 + kc * 4)
                                  : (B1 + (size_t)(n0 + r) * ldb1 + (k0 - kb) + kc * 4);
      const float4 b4 = *(const float4*)bp;
      Bs[kc*4+0][r] = b4.x; Bs[kc*4+1][r] = b4.y; Bs[kc*4+2][r] = b4.z; Bs[kc*4+3][r] = b4.w;
    }
    __syncthreads();
#pragma unroll
    for (int kk = 0; kk < 16; ++kk) {
      float av[8], bv[8];
#pragma unroll
      for (int q = 0; q < 8; ++q) av[q] = As[kk][ta*8+q];
#pragma unroll
      for (int q = 0; q < 8; ++q) bv[q] = Bs[kk][tn*8+q];
#pragma unroll
      for (int ri = 0; ri < 8; ++ri)
#pragma unroll
        for (int ni = 0; ni < 8; ++ni)
          acc[ri][ni] = fmaf(av[ri], bv[ni], acc[ri][ni]);
    }
    __syncthreads();
  }
#pragma unroll
  for (int ri = 0; ri < 8; ++ri) {
    const int i = ta * 8 + ri;
    float* p = P + ((size_t)blockIdx.y * BSZ + i) * N + n0 + tn * 8;
    *(float4*)(p + 0) = make_float4(acc[ri][0], acc[ri][1], acc[ri][2], acc[ri][3]);
    *(float4*)(p + 4) = make_float4(acc[ri][4], acc[ri][5], acc[ri][6], acc[ri][7]);
  }
}

// ---------------- reduce gate partials + LSTM cell update (writes c, xh h-part)
__global__ __launch_bounds__(512) void k_lstm(
    const float* __restrict__ gp, const float* __restrict__ b_ih,
    const float* __restrict__ b_hh, float* __restrict__ cst, float* __restrict__ xh) {
  const int b = blockIdx.x, j = threadIdx.x;
  float g[4];
#pragma unroll
  for (int q = 0; q < 4; ++q) {
    float s = b_ih[q*HIDD + j] + b_hh[q*HIDD + j];
#pragma unroll
    for (int ks = 0; ks < KSG; ++ks) s += gp[((size_t)ks*BSZ + b)*G4D + q*HIDD + j];
    g[q] = s;
  }
  const float c_old = cst[(size_t)b*HIDD + j];
  const float ig = 1.0f / (1.0f + expf(-g[0]));
  const float fg = 1.0f / (1.0f + expf(-g[1]));
  const float gg = tanhf(g[2]);
  const float og = 1.0f / (1.0f + expf(-g[3]));
  const float cn = fg * c_old + ig * gg;
  const float hn = og * tanhf(cn);
  cst[(size_t)b*HIDD + j] = cn;
  xh[(size_t)b*KXD + IND + j] = hn;
}

// ---------------- scores partial: psc[b][mh][n] = sum_{m in mh-range} tanh(cp+hp)*w2
template<typename CPT>
__global__ __launch_bounds__(256) void k_scores(
    const CPT* __restrict__ cp, const float* __restrict__ hpp,
    const float* __restrict__ w2, float* __restrict__ psc) {
  const int mh = blockIdx.x;  // [0,MSPLIT)
  const int b = blockIdx.y;
  const int tid = threadIdx.x;
  __shared__ float hs[128], ws[128];
  if (tid < 128) {
    const int m = mh * 128 + tid;
    float s = 0.0f;
#pragma unroll
    for (int ks = 0; ks < KSH; ++ks) s += hpp[((size_t)ks*BSZ + b)*MLPD + m];
    hs[tid] = s;
    ws[tid] = w2[m];
  }
  __syncthreads();
  const int n0 = tid * 4;
  float ax = 0, ay = 0, az = 0, aw = 0;
  const CPT* base = cp + ((size_t)b * MLPD + mh * 128) * NSQ + n0;
#pragma unroll 4
  for (int mm = 0; mm < 128; ++mm) {
    const float4 c4 = cp_load(base + (size_t)mm * NSQ);
    const float h = hs[mm], w = ws[mm];
    ax = fmaf(tanh_fast(c4.x + h), w, ax);
    ay = fmaf(tanh_fast(c4.y + h), w, ay);
    az = fmaf(tanh_fast(c4.z + h), w, az);
    aw = fmaf(tanh_fast(c4.w + h), w, aw);
  }
  *(float4*)(psc + ((size_t)b * MSPLIT + mh) * NSQ + n0) = make_float4(ax, ay, az, aw);
}

// ---------------- argmax + LSE + lp + mask/x update (one block per batch row)
__global__ __launch_bounds__(256) void k_argmax(
    const float* __restrict__ psc, float* __restrict__ mask,
    const float* __restrict__ gum, const float* __restrict__ b2p,
    float* __restrict__ lp, const float* __restrict__ ctx,
    float* __restrict__ xh, float* __restrict__ outv, int step) {
  const int b = blockIdx.x, tid = threadIdx.x;
  __shared__ float rv[256], rs[256], rm[256];
  __shared__ int ri[256];
  __shared__ int sel;
  const float b2 = b2p[0];
  const int n0 = tid * 4;
  const float4 m4 = *(const float4*)(mask + (size_t)b * NSQ + n0);
  float sc[4] = {b2 + m4.x, b2 + m4.y, b2 + m4.z, b2 + m4.w};
#pragma unroll
  for (int mh = 0; mh < MSPLIT; ++mh) {
    const float4 p4 = *(const float4*)(psc + ((size_t)b * MSPLIT + mh) * NSQ + n0);
    sc[0] += p4.x; sc[1] += p4.y; sc[2] += p4.z; sc[3] += p4.w;
  }
  const float4 g4 = *(const float4*)(gum + ((size_t)step * BSZ + b) * NSQ + n0);
  const float gv[4] = {g4.x, g4.y, g4.z, g4.w};
  float bestv = -1e30f, bests = 0.0f, msc = -1e30f;
  int bestn = 0;
#pragma unroll
  for (int q = 0; q < 4; ++q) {
    const float v = sc[q] + gv[q];
    if (v > bestv) { bestv = v; bestn = n0 + q; bests = sc[q]; }
    msc = fmaxf(msc, sc[q]);
  }
  rv[tid] = bestv; ri[tid] = bestn; rs[tid] = bests; rm[tid] = msc;
  __syncthreads();
  for (int o = 128; o > 0; o >>= 1) {
    if (tid < o) {
      if (rv[tid+o] > rv[tid] || (rv[tid+o] == rv[tid] && ri[tid+o] < ri[tid])) {
        rv[tid] = rv[tid+o]; ri[tid] = ri[tid+o]; rs[tid] = rs[tid+o];
      }
      rm[tid] = fmaxf(rm[tid], rm[tid+o]);
    }
    __syncthreads();
  }
  const float M = rm[0];
  __syncthreads();
  float se = 0.0f;
#pragma unroll
  for (int q = 0; q < 4; ++q)
    se += __builtin_amdgcn_exp2f((sc[q] - M) * 1.4426950408889634f);
  rm[tid] = se;
  __syncthreads();
  for (int o = 128; o > 0; o >>= 1) {
    if (tid < o) rm[tid] += rm[tid+o];
    __syncthreads();
  }
  if (tid == 0) {
    const int n = ri[0];
    const float lse = M + logf(rm[0]);
    const float nlp = lp[b] + rs[0] - lse;
    lp[b] = nlp;
    mask[(size_t)b * NSQ + n] = NEGV;
    outv[step * BSZ + b] = (float)n;
    if (step == NSTEPC - 1) outv[NSTEPC * BSZ + b] = nlp;
    sel = n;
  }
  __syncthreads();
  const int n = sel;
  const float4* src = (const float4*)(ctx + ((size_t)b * NSQ + n) * IND);
  float4* dst = (float4*)(xh + (size_t)b * KXD);
  for (int d = tid; d < IND / 4; d += 256) dst[d] = src[d];
}

extern "C" void kernel_launch(void* const* d_in, const int* in_sizes, int n_in,
                              void* d_out, int out_size, void* d_ws, size_t ws_size,
                              hipStream_t stream) {
  const float* target_emb = (const float*)d_in[0];
  const float* ctx_emb   = (const float*)d_in[1];
  const int*   ctx_len   = (const int*)d_in[3];
  const float* W_ih = (const float*)d_in[5];
  const float* W_hh = (const float*)d_in[6];
  const float* b_ih = (const float*)d_in[7];
  const float* b_hh = (const float*)d_in[8];
  const float* W1c  = (const float*)d_in[9];
  const float* W1h  = (const float*)d_in[10];
  const float* b1   = (const float*)d_in[11];
  const float* w2   = (const float*)d_in[12];
  const float* b2   = (const float*)d_in[13];
  const float* gumbel = (const float*)d_in[14];
  float* out = (float*)d_out;

  float* ws = (float*)d_ws;
  size_t off = 0;
  auto alloc = [&](size_t n) { float* p = ws + off; off += (n + 63) & ~(size_t)63; return p; };

  const size_t cp_elems = (size_t)BSZ * MLPD * NSQ;              // 67.1M
  const size_t fixed_elems = (size_t)KSG*BSZ*G4D + (size_t)KSH*BSZ*MLPD
                           + (size_t)BSZ*MSPLIT*NSQ + (size_t)BSZ*NSQ
                           + (size_t)BSZ*KXD + (size_t)BSZ*HIDD + 1024;
  const bool useF32 = ws_size >= (cp_elems + fixed_elems + 4096) * 4;

  void* cp_raw = (void*)alloc(useF32 ? cp_elems : (cp_elems + 1) / 2);
  float* gp   = alloc((size_t)KSG * BSZ * G4D);
  float* hpp  = alloc((size_t)KSH * BSZ * MLPD);
  float* psc  = alloc((size_t)BSZ * MSPLIT * NSQ);
  float* mask = alloc((size_t)BSZ * NSQ);
  float* xh   = alloc((size_t)BSZ * KXD);
  float* cst  = alloc((size_t)BSZ * HIDD);
  float* lp   = alloc(128);

  k_init<<<BSZ, 256, 0, stream>>>(target_emb, ctx_len, mask, xh, cst, lp);

  if (useF32)
    k_ctx_gemm<float><<<dim3(MLPD/128, (BSZ*NSQ)/128), 256, 0, stream>>>(
        ctx_emb, W1c, b1, (float*)cp_raw);
  else
    k_ctx_gemm<__hip_bfloat16><<<dim3(MLPD/128, (BSZ*NSQ)/128), 256, 0, stream>>>(
        ctx_emb, W1c, b1, (__hip_bfloat16*)cp_raw);

  for (int t = 0; t < NSTEPC; ++t) {
    // gates partials: N=2048, K=1280 split in 16 chunks of 5 tiles
    k_pgemm<<<dim3(G4D/128, KSG), 256, 0, stream>>>(
        xh, KXD, 0, W_ih, IND, IND, W_hh, HIDD, 5, G4D, gp);
    k_lstm<<<BSZ, 512, 0, stream>>>(gp, b_ih, b_hh, cst, xh);
    // hproj partials: N=512, K=512 split in 8 chunks of 4 tiles
    k_pgemm<<<dim3(MLPD/128, KSH), 256, 0, stream>>>(
        xh, KXD, IND, W1h, HIDD, 1 << 30, nullptr, 0, 4, MLPD, hpp);
    if (useF32)
      k_scores<float><<<dim3(MSPLIT, BSZ), 256, 0, stream>>>(
          (const float*)cp_raw, hpp, w2, psc);
    else
      k_scores<__hip_bfloat16><<<dim3(MSPLIT, BSZ), 256, 0, stream>>>(
          (const __hip_bfloat16*)cp_raw, hpp, w2, psc);
    k_argmax<<<BSZ, 256, 0, stream>>>(psc, mask, gumbel, b2, lp, ctx_emb, xh, out, t);
  }
}

// Round 2
// 909.236 us; speedup vs baseline: 2.0351x; 2.0351x over previous
//
#include <hip/hip_runtime.h>
#include <hip/hip_bf16.h>

#define BSZ 128
#define NSQ 1024
#define NSTEPC 8
#define IND 768
#define HIDD 512
#define G4D 2048
#define MLPD 512
#define KXD 1280
#define NEGV -100000.0f
#define KSG 16   // K-split chunks for gates gemm (1280/16 = 80 = 5 tiles)
#define KSH 8    // K-split chunks for hproj gemm (512/8 = 64 = 4 tiles)
#define MSPLIT 4 // m-split for scores kernel

typedef __attribute__((ext_vector_type(4))) float f32x4;
typedef __attribute__((ext_vector_type(8))) short short8v;

__device__ __forceinline__ float bf2f(unsigned short u) {
  unsigned int x = ((unsigned int)u) << 16;
  return __builtin_bit_cast(float, x);
}

// tanh(x) = 1 - 2/(e^{2x}+1)
__device__ __forceinline__ float tanh_fast(float x) {
  x = fminf(fmaxf(x, -15.0f), 15.0f);
  float e = __builtin_amdgcn_exp2f(x * 2.8853900817779268f); // e^{2x}
  float r = __builtin_amdgcn_rcpf(e + 1.0f);
  return fmaf(-2.0f, r, 1.0f);
}

// ---------------- init: mask from ctx_len, xh = [target_emb | 0], c=0, lp=0
__global__ __launch_bounds__(256) void k_init(
    const float* __restrict__ te, const int* __restrict__ cl,
    float* __restrict__ mask, float* __restrict__ xh,
    float* __restrict__ cst, float* __restrict__ lp) {
  const int b = blockIdx.x, tid = threadIdx.x;
  const int L = cl[b];
  for (int n = tid; n < NSQ; n += 256) mask[(size_t)b*NSQ + n] = (n >= L) ? NEGV : 0.0f;
  for (int d = tid; d < IND; d += 256) xh[(size_t)b*KXD + d] = te[(size_t)b*IND + d];
  for (int j = tid; j < HIDD; j += 256) {
    xh[(size_t)b*KXD + IND + j] = 0.0f;
    cst[(size_t)b*HIDD + j] = 0.0f;
  }
  if (tid == 0) lp[b] = 0.0f;
}

// ---------------- ctx_part via split-bf16 MFMA:
// cp[b][m][n] = sum_k ctx[b,n,k]*W1c[m,k] + b1[m]
// Computed as D[m][n] with A-operand = W1c rows (m), B-operand = ctx rows (n),
// both [row][k] in LDS as hi/lo bf16. 3 MFMAs per product: hh + hl + lh.
// BM(m)=128, BN(n)=128, BK=32, 4 waves (2m x 2n), each wave 64x64.
__global__ __launch_bounds__(256) void k_ctx_mfma(
    const float* __restrict__ A,    // ctx_emb [BSZ*NSQ][IND]
    const float* __restrict__ W,    // W1c [MLPD][IND]
    const float* __restrict__ bias, // b1
    const int* __restrict__ clen,
    float* __restrict__ cp) {
  __shared__ short sCh[128*32], sCl[128*32], sWh[128*32], sWl[128*32];
  __shared__ float sb1[128];
  const int m0 = blockIdx.x * 128;
  const int i0 = blockIdx.y * 128;
  const int b = i0 >> 10;
  const int nbase = i0 & 1023;
  if (nbase >= clen[b]) return;   // masked region: cp never read there
  const int tid = threadIdx.x;
  if (tid < 128) sb1[tid] = bias[m0 + tid];
  const int lane = tid & 63;
  const int wid = tid >> 6;
  const int wm = wid & 1, wn = wid >> 1;
  const int l15 = lane & 15, l4 = lane >> 4;

  f32x4 acc[4][4] = {};  // [fm][fn]

  for (int k0 = 0; k0 < IND; k0 += 32) {
#pragma unroll
    for (int u = 0; u < 2; ++u) {
      const int c = tid + u * 256;          // 512 chunks: 128 rows x 4 kc
      const int row = c >> 2, kcs = c & 3;  // storage chunk slot
      const int kread = kcs ^ ((row >> 1) & 3); // pre-swizzled global chunk
      const int off = row * 32 + kcs * 8;
      {
        const float* s = W + (size_t)(m0 + row) * IND + k0 + kread * 8;
        const float4 f0 = *(const float4*)s, f1 = *(const float4*)(s + 4);
        const float fv[8] = {f0.x, f0.y, f0.z, f0.w, f1.x, f1.y, f1.z, f1.w};
        short8v hi, lo;
#pragma unroll
        for (int j = 0; j < 8; ++j) {
          const unsigned int ub = __builtin_bit_cast(unsigned int, fv[j]);
          const unsigned int hb = ub & 0xFFFF0000u;
          const float lf = fv[j] - __builtin_bit_cast(float, hb);
          hi[j] = (short)(hb >> 16);
          lo[j] = (short)(__builtin_bit_cast(unsigned int, lf) >> 16);
        }
        *(short8v*)&sWh[off] = hi;
        *(short8v*)&sWl[off] = lo;
      }
      {
        const float* s = A + (size_t)(i0 + row) * IND + k0 + kread * 8;
        const float4 f0 = *(const float4*)s, f1 = *(const float4*)(s + 4);
        const float fv[8] = {f0.x, f0.y, f0.z, f0.w, f1.x, f1.y, f1.z, f1.w};
        short8v hi, lo;
#pragma unroll
        for (int j = 0; j < 8; ++j) {
          const unsigned int ub = __builtin_bit_cast(unsigned int, fv[j]);
          const unsigned int hb = ub & 0xFFFF0000u;
          const float lf = fv[j] - __builtin_bit_cast(float, hb);
          hi[j] = (short)(hb >> 16);
          lo[j] = (short)(__builtin_bit_cast(unsigned int, lf) >> 16);
        }
        *(short8v*)&sCh[off] = hi;
        *(short8v*)&sCl[off] = lo;
      }
    }
    __syncthreads();
    short8v wh[4], wl[4], chv[4], clv[4];
#pragma unroll
    for (int f = 0; f < 4; ++f) {
      const int rw = wm * 64 + f * 16 + l15;
      const int offw = rw * 32 + ((l4 ^ ((rw >> 1) & 3)) << 3);
      wh[f] = *(const short8v*)&sWh[offw];
      wl[f] = *(const short8v*)&sWl[offw];
      const int rc = wn * 64 + f * 16 + l15;
      const int offc = rc * 32 + ((l4 ^ ((rc >> 1) & 3)) << 3);
      chv[f] = *(const short8v*)&sCh[offc];
      clv[f] = *(const short8v*)&sCl[offc];
    }
#pragma unroll
    for (int fm = 0; fm < 4; ++fm)
#pragma unroll
      for (int fn = 0; fn < 4; ++fn) {
        acc[fm][fn] = __builtin_amdgcn_mfma_f32_16x16x32_bf16(wh[fm], chv[fn], acc[fm][fn], 0, 0, 0);
        acc[fm][fn] = __builtin_amdgcn_mfma_f32_16x16x32_bf16(wh[fm], clv[fn], acc[fm][fn], 0, 0, 0);
        acc[fm][fn] = __builtin_amdgcn_mfma_f32_16x16x32_bf16(wl[fm], chv[fn], acc[fm][fn], 0, 0, 0);
      }
    __syncthreads();
  }
  // epilogue: D row = m = (l>>4)*4 + reg, D col = n = l&15  (16-lane 64B segments)
#pragma unroll
  for (int fm = 0; fm < 4; ++fm) {
#pragma unroll
    for (int r = 0; r < 4; ++r) {
      const int m = m0 + wm * 64 + fm * 16 + l4 * 4 + r;
      const float bb = sb1[m - m0];
      float* dst = cp + (((size_t)(b * MLPD + m)) << 10) + nbase + wn * 64 + l15;
#pragma unroll
      for (int fn = 0; fn < 4; ++fn)
        dst[fn * 16] = acc[fm][fn][r] + bb;
    }
  }
}

// ---------------- K-split partial GEMM: P[kc][i][n] = sum_{k in chunk} A[i,acol+k]*B(n,k)
__global__ __launch_bounds__(256) void k_pgemm(
    const float* __restrict__ A, int lda, int acol,
    const float* __restrict__ B0, int ldb0, int kb,
    const float* __restrict__ B1, int ldb1,
    int kTiles, int N, float* __restrict__ P) {
  __shared__ float As[16][128];
  __shared__ float Bs[16][132];
  const int n0 = blockIdx.x * 128;
  const int kc0 = blockIdx.y * kTiles * 16;
  const int tid = threadIdx.x;
  const int tn = tid & 15;   // n-group
  const int ta = tid >> 4;   // i-group
  float acc[8][8] = {};      // [ri][ni]
  for (int t = 0; t < kTiles; ++t) {
    const int k0 = kc0 + t * 16;
#pragma unroll
    for (int u = 0; u < 2; ++u) {
      const int v = tid + u * 256;
      const int r = v >> 2, kc = v & 3;
      const float4 a4 = *(const float4*)(A + (size_t)r * lda + acol + k0 + kc * 4);
      As[kc*4+0][r] = a4.x; As[kc*4+1][r] = a4.y; As[kc*4+2][r] = a4.z; As[kc*4+3][r] = a4.w;
      const float* bp = (k0 < kb) ? (B0 + (size_t)(n0 + r) * ldb0 + k0 + kc * 4)
                                  : (B1 + (size_t)(n0 + r) * ldb1 + (k0 - kb) + kc * 4);
      const float4 b4 = *(const float4*)bp;
      Bs[kc*4+0][r] = b4.x; Bs[kc*4+1][r] = b4.y; Bs[kc*4+2][r] = b4.z; Bs[kc*4+3][r] = b4.w;
    }
    __syncthreads();
#pragma unroll
    for (int kk = 0; kk < 16; ++kk) {
      float av[8], bv[8];
#pragma unroll
      for (int q = 0; q < 8; ++q) av[q] = As[kk][ta*8+q];
#pragma unroll
      for (int q = 0; q < 8; ++q) bv[q] = Bs[kk][tn*8+q];
#pragma unroll
      for (int ri = 0; ri < 8; ++ri)
#pragma unroll
        for (int ni = 0; ni < 8; ++ni)
          acc[ri][ni] = fmaf(av[ri], bv[ni], acc[ri][ni]);
    }
    __syncthreads();
  }
#pragma unroll
  for (int ri = 0; ri < 8; ++ri) {
    const int i = ta * 8 + ri;
    float* p = P + ((size_t)blockIdx.y * BSZ + i) * N + n0 + tn * 8;
    *(float4*)(p + 0) = make_float4(acc[ri][0], acc[ri][1], acc[ri][2], acc[ri][3]);
    *(float4*)(p + 4) = make_float4(acc[ri][4], acc[ri][5], acc[ri][6], acc[ri][7]);
  }
}

// ---------------- reduce gate partials + LSTM cell update (writes c, xh h-part)
__global__ __launch_bounds__(512) void k_lstm(
    const float* __restrict__ gp, const float* __restrict__ b_ih,
    const float* __restrict__ b_hh, float* __restrict__ cst, float* __restrict__ xh) {
  const int b = blockIdx.x, j = threadIdx.x;
  float g[4];
#pragma unroll
  for (int q = 0; q < 4; ++q) {
    float s = b_ih[q*HIDD + j] + b_hh[q*HIDD + j];
#pragma unroll
    for (int ks = 0; ks < KSG; ++ks) s += gp[((size_t)ks*BSZ + b)*G4D + q*HIDD + j];
    g[q] = s;
  }
  const float c_old = cst[(size_t)b*HIDD + j];
  const float ig = 1.0f / (1.0f + expf(-g[0]));
  const float fg = 1.0f / (1.0f + expf(-g[1]));
  const float gg = tanhf(g[2]);
  const float og = 1.0f / (1.0f + expf(-g[3]));
  const float cn = fg * c_old + ig * gg;
  const float hn = og * tanhf(cn);
  cst[(size_t)b*HIDD + j] = cn;
  xh[(size_t)b*KXD + IND + j] = hn;
}

// ---------------- scores partial: psc[b][mh][n] = sum_{m in mh-range} tanh(cp+hp)*w2
// n >= ctx_len[b] is masked to -1e5 downstream: skip (exact, exp underflows to 0)
__global__ __launch_bounds__(256) void k_scores(
    const float* __restrict__ cp, const float* __restrict__ hpp,
    const float* __restrict__ w2, const int* __restrict__ clen,
    float* __restrict__ psc) {
  const int mh = blockIdx.x;  // [0,MSPLIT)
  const int b = blockIdx.y;
  const int tid = threadIdx.x;
  __shared__ float hs[128], ws[128];
  if (tid < 128) {
    const int m = mh * 128 + tid;
    float s = 0.0f;
#pragma unroll
    for (int ks = 0; ks < KSH; ++ks) s += hpp[((size_t)ks*BSZ + b)*MLPD + m];
    hs[tid] = s;
    ws[tid] = w2[m];
  }
  __syncthreads();
  const int len = clen[b];
  const int n0 = tid * 4;
  if (n0 >= len) return;
  float ax = 0, ay = 0, az = 0, aw = 0;
  const float* base = cp + ((size_t)b * MLPD + mh * 128) * NSQ + n0;
#pragma unroll 4
  for (int mm = 0; mm < 128; ++mm) {
    const float4 c4 = *(const float4*)(base + (size_t)mm * NSQ);
    const float h = hs[mm], w = ws[mm];
    ax = fmaf(tanh_fast(c4.x + h), w, ax);
    ay = fmaf(tanh_fast(c4.y + h), w, ay);
    az = fmaf(tanh_fast(c4.z + h), w, az);
    aw = fmaf(tanh_fast(c4.w + h), w, aw);
  }
  *(float4*)(psc + ((size_t)b * MSPLIT + mh) * NSQ + n0) = make_float4(ax, ay, az, aw);
}

// ---------------- argmax + LSE + lp + mask/x update (one block per batch row)
// psc beyond ctx_len may be stale; mask=-1e5 makes it irrelevant (exp -> 0)
__global__ __launch_bounds__(256) void k_argmax(
    const float* __restrict__ psc, float* __restrict__ mask,
    const float* __restrict__ gum, const float* __restrict__ b2p,
    float* __restrict__ lp, const float* __restrict__ ctx,
    float* __restrict__ xh, float* __restrict__ outv, int step) {
  const int b = blockIdx.x, tid = threadIdx.x;
  __shared__ float rv[256], rs[256], rm[256];
  __shared__ int ri[256];
  __shared__ int sel;
  const float b2 = b2p[0];
  const int n0 = tid * 4;
  const float4 m4 = *(const float4*)(mask + (size_t)b * NSQ + n0);
  float sc[4] = {b2 + m4.x, b2 + m4.y, b2 + m4.z, b2 + m4.w};
#pragma unroll
  for (int mh = 0; mh < MSPLIT; ++mh) {
    const float4 p4 = *(const float4*)(psc + ((size_t)b * MSPLIT + mh) * NSQ + n0);
    sc[0] += p4.x; sc[1] += p4.y; sc[2] += p4.z; sc[3] += p4.w;
  }
  const float4 g4 = *(const float4*)(gum + ((size_t)step * BSZ + b) * NSQ + n0);
  const float gv[4] = {g4.x, g4.y, g4.z, g4.w};
  float bestv = -1e30f, bests = 0.0f, msc = -1e30f;
  int bestn = 0;
#pragma unroll
  for (int q = 0; q < 4; ++q) {
    const float v = sc[q] + gv[q];
    if (v > bestv) { bestv = v; bestn = n0 + q; bests = sc[q]; }
    msc = fmaxf(msc, sc[q]);
  }
  rv[tid] = bestv; ri[tid] = bestn; rs[tid] = bests; rm[tid] = msc;
  __syncthreads();
  for (int o = 128; o > 0; o >>= 1) {
    if (tid < o) {
      if (rv[tid+o] > rv[tid] || (rv[tid+o] == rv[tid] && ri[tid+o] < ri[tid])) {
        rv[tid] = rv[tid+o]; ri[tid] = ri[tid+o]; rs[tid] = rs[tid+o];
      }
      rm[tid] = fmaxf(rm[tid], rm[tid+o]);
    }
    __syncthreads();
  }
  const float M = rm[0];
  __syncthreads();
  float se = 0.0f;
#pragma unroll
  for (int q = 0; q < 4; ++q)
    se += __builtin_amdgcn_exp2f((sc[q] - M) * 1.4426950408889634f);
  rm[tid] = se;
  __syncthreads();
  for (int o = 128; o > 0; o >>= 1) {
    if (tid < o) rm[tid] += rm[tid+o];
    __syncthreads();
  }
  if (tid == 0) {
    const int n = ri[0];
    const float lse = M + logf(rm[0]);
    const float nlp = lp[b] + rs[0] - lse;
    lp[b] = nlp;
    mask[(size_t)b * NSQ + n] = NEGV;
    outv[step * BSZ + b] = (float)n;
    if (step == NSTEPC - 1) outv[NSTEPC * BSZ + b] = nlp;
    sel = n;
  }
  __syncthreads();
  const int n = sel;
  const float4* src = (const float4*)(ctx + ((size_t)b * NSQ + n) * IND);
  float4* dst = (float4*)(xh + (size_t)b * KXD);
  for (int d = tid; d < IND / 4; d += 256) dst[d] = src[d];
}

extern "C" void kernel_launch(void* const* d_in, const int* in_sizes, int n_in,
                              void* d_out, int out_size, void* d_ws, size_t ws_size,
                              hipStream_t stream) {
  const float* target_emb = (const float*)d_in[0];
  const float* ctx_emb   = (const float*)d_in[1];
  const int*   ctx_len   = (const int*)d_in[3];
  const float* W_ih = (const float*)d_in[5];
  const float* W_hh = (const float*)d_in[6];
  const float* b_ih = (const float*)d_in[7];
  const float* b_hh = (const float*)d_in[8];
  const float* W1c  = (const float*)d_in[9];
  const float* W1h  = (const float*)d_in[10];
  const float* b1   = (const float*)d_in[11];
  const float* w2   = (const float*)d_in[12];
  const float* b2   = (const float*)d_in[13];
  const float* gumbel = (const float*)d_in[14];
  float* out = (float*)d_out;

  float* ws = (float*)d_ws;
  size_t off = 0;
  auto alloc = [&](size_t n) { float* p = ws + off; off += (n + 63) & ~(size_t)63; return p; };

  float* cp   = alloc((size_t)BSZ * MLPD * NSQ);   // 268 MB, f32
  float* gp   = alloc((size_t)KSG * BSZ * G4D);
  float* hpp  = alloc((size_t)KSH * BSZ * MLPD);
  float* psc  = alloc((size_t)BSZ * MSPLIT * NSQ);
  float* mask = alloc((size_t)BSZ * NSQ);
  float* xh   = alloc((size_t)BSZ * KXD);
  float* cst  = alloc((size_t)BSZ * HIDD);
  float* lp   = alloc(128);

  k_init<<<BSZ, 256, 0, stream>>>(target_emb, ctx_len, mask, xh, cst, lp);

  k_ctx_mfma<<<dim3(MLPD/128, (BSZ*NSQ)/128), 256, 0, stream>>>(
      ctx_emb, W1c, b1, ctx_len, cp);

  for (int t = 0; t < NSTEPC; ++t) {
    // gates partials: N=2048, K=1280 split in 16 chunks of 5 tiles
    k_pgemm<<<dim3(G4D/128, KSG), 256, 0, stream>>>(
        xh, KXD, 0, W_ih, IND, IND, W_hh, HIDD, 5, G4D, gp);
    k_lstm<<<BSZ, 512, 0, stream>>>(gp, b_ih, b_hh, cst, xh);
    // hproj partials: N=512, K=512 split in 8 chunks of 4 tiles
    k_pgemm<<<dim3(MLPD/128, KSH), 256, 0, stream>>>(
        xh, KXD, IND, W1h, HIDD, 1 << 30, nullptr, 0, 4, MLPD, hpp);
    k_scores<<<dim3(MSPLIT, BSZ), 256, 0, stream>>>(cp, hpp, w2, ctx_len, psc);
    k_argmax<<<BSZ, 256, 0, stream>>>(psc, mask, gumbel, b2, lp, ctx_emb, xh, out, t);
  }
}